// Round 8
// baseline (49.950 us; speedup 1.0000x reference)
//
#include <hip/hip_runtime.h>
#include <hip/hip_bf16.h>
#include <math.h>

#define NN 4096
#define CC 64
#define LOG2E 1.44269504f

typedef float  f32x16 __attribute__((ext_vector_type(16)));
typedef short  bf16x8 __attribute__((ext_vector_type(8)));
typedef short  s16x4  __attribute__((ext_vector_type(4)));
typedef unsigned int u32x4 __attribute__((ext_vector_type(4)));

static __device__ __forceinline__ unsigned short f2bfu(float f) {
    __hip_bfloat16 h = __float2bfloat16(f);
    unsigned short s;
    __builtin_memcpy(&s, &h, 2);
    return s;
}
static __device__ __forceinline__ unsigned packbf(float lo, float hi) {
    return (unsigned)f2bfu(lo) | ((unsigned)f2bfu(hi) << 16);
}
static __device__ __forceinline__ float exp2_fast(float x) {
    float r;
    asm("v_exp_f32 %0, %1" : "=v"(r) : "v"(x));
    return r;
}
static __device__ __forceinline__ f32x16 fzero16() {
    f32x16 z;
#pragma unroll
    for (int i = 0; i < 16; ++i) z[i] = 0.f;
    return z;
}
static __device__ __forceinline__ bf16x8 bzero8() {
    bf16x8 z;
#pragma unroll
    for (int i = 0; i < 8; ++i) z[i] = 0;
    return z;
}

// ---------------------------------------------------------------------------
// K1: fused projection (q,k,v) via MFMA.  Grid 384x256: rt = blk>>7 (3 row
// tiles of W rows 0-95), nt = (blk&127)*4+w.  Writes qb[n][8] (q * LOG2E),
// kb[n][8] bf16, and UNSCALED vsT[b*64+c][n] bf16.
// W row map: 0-7 wq, 8-15 wk, 16-79 wv, 80-95 zero.
// ---------------------------------------------------------------------------
__global__ __launch_bounds__(256) void proj_all(
        const float* __restrict__ x,
        const float* __restrict__ wq, const float* __restrict__ bq,
        const float* __restrict__ wk, const float* __restrict__ bk,
        const float* __restrict__ wv, const float* __restrict__ bv,
        short* __restrict__ qb, short* __restrict__ kb, short* __restrict__ vsT) {
    int t = threadIdx.x;
    int w = t >> 6, ml = t & 31, hi = (t >> 5) & 1;
    int rt = blockIdx.x >> 7;
    int nt = (blockIdx.x & 127) * 4 + w;
    int ng = nt * 32 + ml;            // b*4096+n
    int b = ng >> 12, nb_ = ng & 4095;
    const float* xc = x + ((size_t)b * CC) * NN + nb_;

    int rg = 32 * rt + ml;            // my A-row (W row)
    const float* wrow =
        rg < 8  ? wq + (size_t)rg * 64 :
        rg < 16 ? wk + (size_t)(rg - 8) * 64 :
        rg < 80 ? wv + (size_t)(rg - 16) * 64 : wq;
    bool wvalid = (rg < 80);

    f32x16 acc = fzero16();
#pragma unroll
    for (int s = 0; s < 4; ++s) {
        int c0 = 16 * s + 8 * hi;
        float xv[8];
#pragma unroll
        for (int j = 0; j < 8; ++j) xv[j] = xc[(size_t)(c0 + j) * NN];
        u32x4 xg;
#pragma unroll
        for (int j = 0; j < 4; ++j) xg[j] = packbf(xv[2 * j], xv[2 * j + 1]);
        bf16x8 xf = __builtin_bit_cast(bf16x8, xg);

        bf16x8 af;
        if (wvalid) {
            float4 f0 = *(const float4*)(wrow + c0);
            float4 f1 = *(const float4*)(wrow + c0 + 4);
            u32x4 ag;
            ag[0] = packbf(f0.x, f0.y); ag[1] = packbf(f0.z, f0.w);
            ag[2] = packbf(f1.x, f1.y); ag[3] = packbf(f1.z, f1.w);
            af = __builtin_bit_cast(bf16x8, ag);
        } else {
            af = bzero8();
        }
        acc = __builtin_amdgcn_mfma_f32_32x32x16_bf16(af, xf, acc, 0, 0, 0);
    }

    if (rt == 0) {
        s16x4 qv, kv;
#pragma unroll
        for (int j = 0; j < 4; ++j) {
            qv[j] = (short)f2bfu((acc[j] + bq[j + 4 * hi]) * LOG2E);
            kv[j] = (short)f2bfu(acc[j + 4] + bk[j + 4 * hi]);
        }
        *(s16x4*)(qb + (size_t)ng * 8 + 4 * hi) = qv;
        *(s16x4*)(kb + (size_t)ng * 8 + 4 * hi) = kv;
#pragma unroll
        for (int r = 8; r < 16; ++r) {            // rows 16-31 -> v c 0-15
            int rowr = (r & 3) + 8 * (r >> 2) + 4 * hi;
            int c = rowr - 16;
            vsT[((size_t)(b * CC + c)) * NN + nb_] = (short)f2bfu(acc[r] + bv[c]);
        }
    } else if (rt == 1) {
#pragma unroll
        for (int r = 0; r < 16; ++r) {            // rows 32-63 -> v c 16-47
            int rowr = (r & 3) + 8 * (r >> 2) + 4 * hi;
            int c = rowr + 16;
            vsT[((size_t)(b * CC + c)) * NN + nb_] = (short)f2bfu(acc[r] + bv[c]);
        }
    } else {
#pragma unroll
        for (int r = 0; r < 8; ++r) {             // rows 64-79 -> v c 48-63
            int rowr = (r & 3) + 8 * (r >> 2) + 4 * hi;
            int c = rowr + 48;
            vsT[((size_t)(b * CC + c)) * NN + nb_] = (short)f2bfu(acc[r] + bv[c]);
        }
    }
}

// ---------------------------------------------------------------------------
// K2: rinv[b][n] = 1/sum_m 2^(s'[n][m])  (q pre-scaled by LOG2E).
// Grid 512 = b x 128 n-tiles(32); 8 waves m-split, 16 iters, 1-deep prefetch.
// ---------------------------------------------------------------------------
__global__ __launch_bounds__(512) void stats_mfma(
        const short* __restrict__ qb, const short* __restrict__ kb,
        float* __restrict__ rinv) {
    int b = blockIdx.x >> 7;
    int nbase = (blockIdx.x & 127) * 32;
    int t = threadIdx.x;
    int w = __builtin_amdgcn_readfirstlane(t >> 6);
    int ml = t & 31, hi = (t >> 5) & 1;

    bf16x8 qf = bzero8();
    if (!hi) qf = *(const bf16x8*)(qb + ((size_t)(b * NN + nbase + ml)) * 8);
    const short* kbb = kb + ((size_t)b * NN) * 8;

    float accl[16];
#pragma unroll
    for (int r = 0; r < 16; ++r) accl[r] = 0.f;

    bf16x8 kf0 = bzero8();
    if (!hi) kf0 = *(const bf16x8*)(kbb + (size_t)(w * 32 + ml) * 8);

    for (int i = 0; i < 16; ++i) {
        int mchn = (i < 15) ? (w + 8 * (i + 1)) : w;
        bf16x8 kf1 = bzero8();
        if (!hi) kf1 = *(const bf16x8*)(kbb + (size_t)(mchn * 32 + ml) * 8);
        f32x16 s = __builtin_amdgcn_mfma_f32_32x32x16_bf16(qf, kf0, fzero16(), 0, 0, 0);
#pragma unroll
        for (int r = 0; r < 16; ++r) accl[r] += exp2_fast(s[r]);
        kf0 = kf1;
    }

#pragma unroll
    for (int r = 0; r < 16; ++r) {
#pragma unroll
        for (int mask = 1; mask <= 16; mask <<= 1)
            accl[r] += __shfl_xor(accl[r], mask);
    }

    __shared__ float rs[32];
    if (t < 32) rs[t] = 0.f;
    __syncthreads();
    if (ml == 0) {
#pragma unroll
        for (int r = 0; r < 16; ++r) {
            int rowr = (r & 3) + 8 * (r >> 2) + 4 * hi;
            atomicAdd(&rs[rowr], accl[r]);
        }
    }
    __syncthreads();
    if (t < 32) rinv[(size_t)b * NN + nbase + t] = 1.0f / rs[t];
}

// ---------------------------------------------------------------------------
// K3: out[b][c][m] = x + sum_n V[c][n] * (2^(s'[n][m]) * rinv[n]).
// Grid 256 = b x 64 m-tiles(64).  8-wave n-split, 16 iters; each wave owns a
// 64-wide m-tile (kf0,kf1) and 4 acc quadrants.  rinv folded into P before
// the bf16 pack (4 prefetched half-uniform float4 loads/iter).  1-deep
// prefetch of q + 4 V-frags + rv; P in registers via shfl_xor(32); no loop
// barriers.  Two-stage LDS reduce.
// ---------------------------------------------------------------------------
__global__ __launch_bounds__(512, 2) void attn_pv(
        const short* __restrict__ qb, const short* __restrict__ kb,
        const short* __restrict__ vsT, const float* __restrict__ rinv,
        const float* __restrict__ x, float* __restrict__ out) {
    __shared__ float red[4][64][68];

    int b = blockIdx.x >> 6;
    int mbase = (blockIdx.x & 63) << 6;
    int t = threadIdx.x;
    int w = __builtin_amdgcn_readfirstlane(t >> 6);   // 0..7 n-split
    int ml = t & 31, hi = (t >> 5) & 1;

    bf16x8 kf0 = bzero8(), kf1 = bzero8();
    if (!hi) {
        kf0 = *(const bf16x8*)(kb + ((size_t)(b * NN + mbase + ml)) * 8);
        kf1 = *(const bf16x8*)(kb + ((size_t)(b * NN + mbase + 32 + ml)) * 8);
    }

    f32x16 accA = fzero16(), accB = fzero16();   // (c0,m0) (c0,m1)
    f32x16 accC = fzero16(), accD = fzero16();   // (c1,m0) (c1,m1)

    const short* qbb = qb + ((size_t)b * NN) * 8;
    const short* v0p = vsT + ((size_t)(b * CC) + ml) * NN;
    const short* v1p = v0p + (size_t)32 * NN;
    const float* rvb = rinv + (size_t)b * NN;

    int n0 = w * 32;
    bf16x8 qf_c = bzero8();
    if (!hi) qf_c = *(const bf16x8*)(qbb + (size_t)(n0 + ml) * 8);
    bf16x8 a00_c = *(const bf16x8*)(v0p + n0 + 8 * hi);
    bf16x8 a01_c = *(const bf16x8*)(v0p + n0 + 16 + 8 * hi);
    bf16x8 a10_c = *(const bf16x8*)(v1p + n0 + 8 * hi);
    bf16x8 a11_c = *(const bf16x8*)(v1p + n0 + 16 + 8 * hi);
    const float* rvp = rvb + n0 + 4 * hi;
    float4 rv0_c = *(const float4*)(rvp);
    float4 rv1_c = *(const float4*)(rvp + 8);
    float4 rv2_c = *(const float4*)(rvp + 16);
    float4 rv3_c = *(const float4*)(rvp + 24);

    for (int i = 0; i < 16; ++i) {
        int n0n = (i < 15) ? (w + 8 * (i + 1)) * 32 : w * 32;
        bf16x8 qf_n = bzero8();
        if (!hi) qf_n = *(const bf16x8*)(qbb + (size_t)(n0n + ml) * 8);
        bf16x8 a00_n = *(const bf16x8*)(v0p + n0n + 8 * hi);
        bf16x8 a01_n = *(const bf16x8*)(v0p + n0n + 16 + 8 * hi);
        bf16x8 a10_n = *(const bf16x8*)(v1p + n0n + 8 * hi);
        bf16x8 a11_n = *(const bf16x8*)(v1p + n0n + 16 + 8 * hi);
        const float* rvpn = rvb + n0n + 4 * hi;
        float4 rv0_n = *(const float4*)(rvpn);
        float4 rv1_n = *(const float4*)(rvpn + 8);
        float4 rv2_n = *(const float4*)(rvpn + 16);
        float4 rv3_n = *(const float4*)(rvpn + 24);

        f32x16 s0 = __builtin_amdgcn_mfma_f32_32x32x16_bf16(qf_c, kf0, fzero16(), 0, 0, 0);
        f32x16 s1 = __builtin_amdgcn_mfma_f32_32x32x16_bf16(qf_c, kf1, fzero16(), 0, 0, 0);

        // ---- m-half 0: p = 2^s * rinv[row], pack, partner exchange
        unsigned g0 = packbf(exp2_fast(s0[0])  * rv0_c.x, exp2_fast(s0[1])  * rv0_c.y);
        unsigned g1 = packbf(exp2_fast(s0[2])  * rv0_c.z, exp2_fast(s0[3])  * rv0_c.w);
        unsigned g2 = packbf(exp2_fast(s0[4])  * rv1_c.x, exp2_fast(s0[5])  * rv1_c.y);
        unsigned g3 = packbf(exp2_fast(s0[6])  * rv1_c.z, exp2_fast(s0[7])  * rv1_c.w);
        unsigned g4 = packbf(exp2_fast(s0[8])  * rv2_c.x, exp2_fast(s0[9])  * rv2_c.y);
        unsigned g5 = packbf(exp2_fast(s0[10]) * rv2_c.z, exp2_fast(s0[11]) * rv2_c.w);
        unsigned g6 = packbf(exp2_fast(s0[12]) * rv3_c.x, exp2_fast(s0[13]) * rv3_c.y);
        unsigned g7 = packbf(exp2_fast(s0[14]) * rv3_c.z, exp2_fast(s0[15]) * rv3_c.w);
        unsigned gr0 = (unsigned)__shfl_xor((int)(hi ? g0 : g2), 32);
        unsigned gr1 = (unsigned)__shfl_xor((int)(hi ? g1 : g3), 32);
        unsigned gr2 = (unsigned)__shfl_xor((int)(hi ? g4 : g6), 32);
        unsigned gr3 = (unsigned)__shfl_xor((int)(hi ? g5 : g7), 32);
        u32x4 b0u, b1u;
        b0u[0] = hi ? gr0 : g0;  b0u[1] = hi ? gr1 : g1;
        b0u[2] = hi ? g2 : gr0;  b0u[3] = hi ? g3 : gr1;
        b1u[0] = hi ? gr2 : g4;  b1u[1] = hi ? gr3 : g5;
        b1u[2] = hi ? g6 : gr2;  b1u[3] = hi ? g7 : gr3;
        bf16x8 bf00 = __builtin_bit_cast(bf16x8, b0u);
        bf16x8 bf01 = __builtin_bit_cast(bf16x8, b1u);

        // ---- m-half 1 (same rows -> same rv)
        unsigned h0 = packbf(exp2_fast(s1[0])  * rv0_c.x, exp2_fast(s1[1])  * rv0_c.y);
        unsigned h1 = packbf(exp2_fast(s1[2])  * rv0_c.z, exp2_fast(s1[3])  * rv0_c.w);
        unsigned h2 = packbf(exp2_fast(s1[4])  * rv1_c.x, exp2_fast(s1[5])  * rv1_c.y);
        unsigned h3 = packbf(exp2_fast(s1[6])  * rv1_c.z, exp2_fast(s1[7])  * rv1_c.w);
        unsigned h4 = packbf(exp2_fast(s1[8])  * rv2_c.x, exp2_fast(s1[9])  * rv2_c.y);
        unsigned h5 = packbf(exp2_fast(s1[10]) * rv2_c.z, exp2_fast(s1[11]) * rv2_c.w);
        unsigned h6 = packbf(exp2_fast(s1[12]) * rv3_c.x, exp2_fast(s1[13]) * rv3_c.y);
        unsigned h7 = packbf(exp2_fast(s1[14]) * rv3_c.z, exp2_fast(s1[15]) * rv3_c.w);
        unsigned hr0 = (unsigned)__shfl_xor((int)(hi ? h0 : h2), 32);
        unsigned hr1 = (unsigned)__shfl_xor((int)(hi ? h1 : h3), 32);
        unsigned hr2 = (unsigned)__shfl_xor((int)(hi ? h4 : h6), 32);
        unsigned hr3 = (unsigned)__shfl_xor((int)(hi ? h5 : h7), 32);
        u32x4 b2u, b3u;
        b2u[0] = hi ? hr0 : h0;  b2u[1] = hi ? hr1 : h1;
        b2u[2] = hi ? h2 : hr0;  b2u[3] = hi ? h3 : hr1;
        b3u[0] = hi ? hr2 : h4;  b3u[1] = hi ? hr3 : h5;
        b3u[2] = hi ? h6 : hr2;  b3u[3] = hi ? h7 : hr3;
        bf16x8 bf10 = __builtin_bit_cast(bf16x8, b2u);
        bf16x8 bf11 = __builtin_bit_cast(bf16x8, b3u);

        accA = __builtin_amdgcn_mfma_f32_32x32x16_bf16(a00_c, bf00, accA, 0, 0, 0);
        accA = __builtin_amdgcn_mfma_f32_32x32x16_bf16(a01_c, bf01, accA, 0, 0, 0);
        accC = __builtin_amdgcn_mfma_f32_32x32x16_bf16(a10_c, bf00, accC, 0, 0, 0);
        accC = __builtin_amdgcn_mfma_f32_32x32x16_bf16(a11_c, bf01, accC, 0, 0, 0);
        accB = __builtin_amdgcn_mfma_f32_32x32x16_bf16(a00_c, bf10, accB, 0, 0, 0);
        accB = __builtin_amdgcn_mfma_f32_32x32x16_bf16(a01_c, bf11, accB, 0, 0, 0);
        accD = __builtin_amdgcn_mfma_f32_32x32x16_bf16(a10_c, bf10, accD, 0, 0, 0);
        accD = __builtin_amdgcn_mfma_f32_32x32x16_bf16(a11_c, bf11, accD, 0, 0, 0);

        qf_c = qf_n;
        a00_c = a00_n; a01_c = a01_n; a10_c = a10_n; a11_c = a11_n;
        rv0_c = rv0_n; rv1_c = rv1_n; rv2_c = rv2_n; rv3_c = rv3_n;
    }

    // two-stage reduce: waves 4-7 dump, waves 0-3 merge, then final sum
    int q4 = w & 3;
    if (w >= 4) {
#pragma unroll
        for (int r = 0; r < 16; ++r) {
            int rowr = (r & 3) + 8 * (r >> 2) + 4 * hi;
            red[q4][rowr][ml]           = accA[r];
            red[q4][rowr][32 + ml]      = accB[r];
            red[q4][rowr + 32][ml]      = accC[r];
            red[q4][rowr + 32][32 + ml] = accD[r];
        }
    }
    __syncthreads();
    if (w < 4) {
#pragma unroll
        for (int r = 0; r < 16; ++r) {
            int rowr = (r & 3) + 8 * (r >> 2) + 4 * hi;
            red[q4][rowr][ml]           += accA[r];
            red[q4][rowr][32 + ml]      += accB[r];
            red[q4][rowr + 32][ml]      += accC[r];
            red[q4][rowr + 32][32 + ml] += accD[r];
        }
    }
    __syncthreads();

    int c = t >> 3;
    int m0 = (t & 7) << 3;
    float4 s0 = *(float4*)&red[0][c][m0];
    float4 s1 = *(float4*)&red[0][c][m0 + 4];
#pragma unroll
    for (int q = 1; q < 4; ++q) {
        float4 a = *(float4*)&red[q][c][m0];
        float4 b4 = *(float4*)&red[q][c][m0 + 4];
        s0.x += a.x; s0.y += a.y; s0.z += a.z; s0.w += a.w;
        s1.x += b4.x; s1.y += b4.y; s1.z += b4.z; s1.w += b4.w;
    }
    size_t idx = ((size_t)(b * CC + c)) * NN + mbase + m0;
    float4 xa = *(const float4*)(x + idx);
    float4 xb = *(const float4*)(x + idx + 4);
    s0.x += xa.x; s0.y += xa.y; s0.z += xa.z; s0.w += xa.w;
    s1.x += xb.x; s1.y += xb.y; s1.z += xb.z; s1.w += xb.w;
    *(float4*)(out + idx) = s0;
    *(float4*)(out + idx + 4) = s1;
}

// ---------------------------------------------------------------------------
extern "C" void kernel_launch(void* const* d_in, const int* in_sizes, int n_in,
                              void* d_out, int out_size, void* d_ws, size_t ws_size,
                              hipStream_t stream) {
    const float* x  = (const float*)d_in[0];
    const float* wq = (const float*)d_in[1];
    const float* bq = (const float*)d_in[2];
    const float* wk = (const float*)d_in[3];
    const float* bk = (const float*)d_in[4];
    const float* wv = (const float*)d_in[5];
    const float* bv = (const float*)d_in[6];
    float* out = (float*)d_out;

    char* ws = (char*)d_ws;
    short* qb   = (short*)(ws);                              // 256 KB
    short* kb   = (short*)(ws + (256u << 10));               // 256 KB
    short* vsT  = (short*)(ws + (512u << 10));               // 2 MB
    float* rinv = (float*)(ws + (512u << 10) + (2u << 20));  // 64 KB

    proj_all  <<<384, 256, 0, stream>>>(x, wq, bq, wk, bk, wv, bv, qb, kb, vsT);
    stats_mfma<<<512, 512, 0, stream>>>(qb, kb, rinv);
    attn_pv   <<<256, 512, 0, stream>>>(qb, kb, vsT, rinv, x, out);
}

// Round 12
// 48.492 us; speedup vs baseline: 1.0301x; 1.0301x over previous
//
#include <hip/hip_runtime.h>
#include <hip/hip_bf16.h>
#include <math.h>

#define NN 4096
#define CC 64

typedef float  f32x16 __attribute__((ext_vector_type(16)));
typedef short  bf16x8 __attribute__((ext_vector_type(8)));
typedef short  s16x4  __attribute__((ext_vector_type(4)));
typedef unsigned int u32x4 __attribute__((ext_vector_type(4)));

static __device__ __forceinline__ unsigned short f2bfu(float f) {
    __hip_bfloat16 h = __float2bfloat16(f);
    unsigned short s;
    __builtin_memcpy(&s, &h, 2);
    return s;
}
static __device__ __forceinline__ unsigned packbf(float lo, float hi) {
    return (unsigned)f2bfu(lo) | ((unsigned)f2bfu(hi) << 16);
}
static __device__ __forceinline__ f32x16 fzero16() {
    f32x16 z;
#pragma unroll
    for (int i = 0; i < 16; ++i) z[i] = 0.f;
    return z;
}
static __device__ __forceinline__ bf16x8 bzero8() {
    bf16x8 z;
#pragma unroll
    for (int i = 0; i < 8; ++i) z[i] = 0;
    return z;
}

// ---------------------------------------------------------------------------
// K1: fused projection (q,k,v) via MFMA.  Grid 384x256: rt = blk>>7 (3 row
// tiles of W rows 0-95), nt = (blk&127)*4+w.  Writes qb[n][8], kb[n][8] bf16
// and UNSCALED vT[b*64+c][n] fp32.
// ---------------------------------------------------------------------------
__global__ __launch_bounds__(256) void proj_all(
        const float* __restrict__ x,
        const float* __restrict__ wq, const float* __restrict__ bq,
        const float* __restrict__ wk, const float* __restrict__ bk,
        const float* __restrict__ wv, const float* __restrict__ bv,
        short* __restrict__ qb, short* __restrict__ kb, float* __restrict__ vT) {
    int t = threadIdx.x;
    int w = t >> 6, ml = t & 31, hi = (t >> 5) & 1;
    int rt = blockIdx.x >> 7;
    int nt = (blockIdx.x & 127) * 4 + w;
    int ng = nt * 32 + ml;            // b*4096+n
    int b = ng >> 12, nb_ = ng & 4095;
    const float* xc = x + ((size_t)b * CC) * NN + nb_;

    int rg = 32 * rt + ml;            // my A-row (W row)
    const float* wrow =
        rg < 8  ? wq + (size_t)rg * 64 :
        rg < 16 ? wk + (size_t)(rg - 8) * 64 :
        rg < 80 ? wv + (size_t)(rg - 16) * 64 : wq;
    bool wvalid = (rg < 80);

    f32x16 acc = fzero16();
#pragma unroll
    for (int s = 0; s < 4; ++s) {
        int c0 = 16 * s + 8 * hi;
        float xv[8];
#pragma unroll
        for (int j = 0; j < 8; ++j) xv[j] = xc[(size_t)(c0 + j) * NN];
        u32x4 xg;
#pragma unroll
        for (int j = 0; j < 4; ++j) xg[j] = packbf(xv[2 * j], xv[2 * j + 1]);
        bf16x8 xf = __builtin_bit_cast(bf16x8, xg);

        bf16x8 af;
        if (wvalid) {
            float4 f0 = *(const float4*)(wrow + c0);
            float4 f1 = *(const float4*)(wrow + c0 + 4);
            u32x4 ag;
            ag[0] = packbf(f0.x, f0.y); ag[1] = packbf(f0.z, f0.w);
            ag[2] = packbf(f1.x, f1.y); ag[3] = packbf(f1.z, f1.w);
            af = __builtin_bit_cast(bf16x8, ag);
        } else {
            af = bzero8();
        }
        acc = __builtin_amdgcn_mfma_f32_32x32x16_bf16(af, xf, acc, 0, 0, 0);
    }

    if (rt == 0) {
        s16x4 qv, kv;
#pragma unroll
        for (int j = 0; j < 4; ++j) {
            qv[j] = (short)f2bfu(acc[j] + bq[j + 4 * hi]);
            kv[j] = (short)f2bfu(acc[j + 4] + bk[j + 4 * hi]);
        }
        *(s16x4*)(qb + (size_t)ng * 8 + 4 * hi) = qv;
        *(s16x4*)(kb + (size_t)ng * 8 + 4 * hi) = kv;
#pragma unroll
        for (int r = 8; r < 16; ++r) {            // rows 16-31 -> v c 0-15
            int rowr = (r & 3) + 8 * (r >> 2) + 4 * hi;
            int c = rowr - 16;
            vT[((size_t)(b * CC + c)) * NN + nb_] = acc[r] + bv[c];
        }
    } else if (rt == 1) {
#pragma unroll
        for (int r = 0; r < 16; ++r) {            // rows 32-63 -> v c 16-47
            int rowr = (r & 3) + 8 * (r >> 2) + 4 * hi;
            int c = rowr + 16;
            vT[((size_t)(b * CC + c)) * NN + nb_] = acc[r] + bv[c];
        }
    } else {
#pragma unroll
        for (int r = 0; r < 8; ++r) {             // rows 64-79 -> v c 48-63
            int rowr = (r & 3) + 8 * (r >> 2) + 4 * hi;
            int c = rowr + 48;
            vT[((size_t)(b * CC + c)) * NN + nb_] = acc[r] + bv[c];
        }
    }
}

// ---------------------------------------------------------------------------
// K2: rinv[b][n] = 1/sum_m exp(s[n][m]).  Grid 512 = b x 128 n-tiles(32);
// 8 waves m-split, 16 iters each, 1-deep k-fragment prefetch.
// ---------------------------------------------------------------------------
__global__ __launch_bounds__(512) void stats_mfma(
        const short* __restrict__ qb, const short* __restrict__ kb,
        float* __restrict__ rinv) {
    int b = blockIdx.x >> 7;
    int nbase = (blockIdx.x & 127) * 32;
    int t = threadIdx.x;
    int w = __builtin_amdgcn_readfirstlane(t >> 6);
    int ml = t & 31, hi = (t >> 5) & 1;

    bf16x8 qf = bzero8();
    if (!hi) qf = *(const bf16x8*)(qb + ((size_t)(b * NN + nbase + ml)) * 8);
    const short* kbb = kb + ((size_t)b * NN) * 8;

    float accl[16];
#pragma unroll
    for (int r = 0; r < 16; ++r) accl[r] = 0.f;

    bf16x8 kf0 = bzero8();
    if (!hi) kf0 = *(const bf16x8*)(kbb + (size_t)(w * 32 + ml) * 8);

    for (int i = 0; i < 16; ++i) {
        int mchn = (i < 15) ? (w + 8 * (i + 1)) : w;
        bf16x8 kf1 = bzero8();
        if (!hi) kf1 = *(const bf16x8*)(kbb + (size_t)(mchn * 32 + ml) * 8);
        f32x16 s = __builtin_amdgcn_mfma_f32_32x32x16_bf16(qf, kf0, fzero16(), 0, 0, 0);
#pragma unroll
        for (int r = 0; r < 16; ++r) accl[r] += __expf(s[r]);
        kf0 = kf1;
    }

#pragma unroll
    for (int r = 0; r < 16; ++r) {
#pragma unroll
        for (int mask = 1; mask <= 16; mask <<= 1)
            accl[r] += __shfl_xor(accl[r], mask);
    }

    __shared__ float rs[32];
    if (t < 32) rs[t] = 0.f;
    __syncthreads();
    if (ml == 0) {
#pragma unroll
        for (int r = 0; r < 16; ++r) {
            int rowr = (r & 3) + 8 * (r >> 2) + 4 * hi;
            atomicAdd(&rs[rowr], accl[r]);
        }
    }
    __syncthreads();
    if (t < 32) rinv[(size_t)b * NN + nbase + t] = 1.0f / rs[t];
}

// ---------------------------------------------------------------------------
// K3: vsT[c][n] = bf16(vT[c][n] * rinv[n])   (streaming, 8 elems/thread)
// ---------------------------------------------------------------------------
__global__ __launch_bounds__(256) void v_scale(
        const float* __restrict__ vT, const float* __restrict__ rinv,
        short* __restrict__ vsT) {
    int gid = blockIdx.x * 256 + threadIdx.x;   // 131072 threads
    int row = gid >> 9;                         // b*64+c
    int noff = (gid & 511) << 3;
    int b = row >> 6;
    const float* vp = vT + (size_t)row * NN + noff;
    const float* rp = rinv + (size_t)b * NN + noff;
    float4 v0 = *(const float4*)vp, v1 = *(const float4*)(vp + 4);
    float4 r0 = *(const float4*)rp, r1 = *(const float4*)(rp + 4);
    u32x4 o;
    o[0] = packbf(v0.x * r0.x, v0.y * r0.y);
    o[1] = packbf(v0.z * r0.z, v0.w * r0.w);
    o[2] = packbf(v1.x * r1.x, v1.y * r1.y);
    o[3] = packbf(v1.z * r1.z, v1.w * r1.w);
    *(u32x4*)(vsT + (size_t)row * NN + noff) = o;
}

// ---------------------------------------------------------------------------
// K4: out[b][c][m] = x + sum_n Vs[c][n] * exp(s[n][m]).
// Grid 256 = b x 64 m-tiles(64).  8-wave n-split, 16 iters; each wave owns a
// 64-wide m-tile (kf0,kf1) and 4 acc quadrants (c-half x m-half).  A-frags
// (V) are shared across both m-halves -> half the L2 traffic per output.
// 1-deep prefetch of q + 4 V-frags; P in registers via shfl_xor(32); no loop
// barriers.  Two-stage LDS reduce.
// ---------------------------------------------------------------------------
__global__ __launch_bounds__(512, 2) void attn_pv(
        const short* __restrict__ qb, const short* __restrict__ kb,
        const short* __restrict__ vsT,
        const float* __restrict__ x, float* __restrict__ out) {
    __shared__ float red[4][64][68];

    int b = blockIdx.x >> 6;
    int mbase = (blockIdx.x & 63) << 6;
    int t = threadIdx.x;
    int w = __builtin_amdgcn_readfirstlane(t >> 6);   // 0..7 n-split
    int ml = t & 31, hi = (t >> 5) & 1;

    bf16x8 kf0 = bzero8(), kf1 = bzero8();
    if (!hi) {
        kf0 = *(const bf16x8*)(kb + ((size_t)(b * NN + mbase + ml)) * 8);
        kf1 = *(const bf16x8*)(kb + ((size_t)(b * NN + mbase + 32 + ml)) * 8);
    }

    f32x16 accA = fzero16(), accB = fzero16();   // (c0,m0) (c0,m1)
    f32x16 accC = fzero16(), accD = fzero16();   // (c1,m0) (c1,m1)

    const short* qbb = qb + ((size_t)b * NN) * 8;
    const short* v0p = vsT + ((size_t)(b * CC) + ml) * NN;
    const short* v1p = v0p + (size_t)32 * NN;

    int n0 = w * 32;
    bf16x8 qf_c = bzero8();
    if (!hi) qf_c = *(const bf16x8*)(qbb + (size_t)(n0 + ml) * 8);
    bf16x8 a00_c = *(const bf16x8*)(v0p + n0 + 8 * hi);
    bf16x8 a01_c = *(const bf16x8*)(v0p + n0 + 16 + 8 * hi);
    bf16x8 a10_c = *(const bf16x8*)(v1p + n0 + 8 * hi);
    bf16x8 a11_c = *(const bf16x8*)(v1p + n0 + 16 + 8 * hi);

    for (int i = 0; i < 16; ++i) {
        int n0n = (i < 15) ? (w + 8 * (i + 1)) * 32 : w * 32;
        bf16x8 qf_n = bzero8();
        if (!hi) qf_n = *(const bf16x8*)(qbb + (size_t)(n0n + ml) * 8);
        bf16x8 a00_n = *(const bf16x8*)(v0p + n0n + 8 * hi);
        bf16x8 a01_n = *(const bf16x8*)(v0p + n0n + 16 + 8 * hi);
        bf16x8 a10_n = *(const bf16x8*)(v1p + n0n + 8 * hi);
        bf16x8 a11_n = *(const bf16x8*)(v1p + n0n + 16 + 8 * hi);

        f32x16 s0 = __builtin_amdgcn_mfma_f32_32x32x16_bf16(qf_c, kf0, fzero16(), 0, 0, 0);
        f32x16 s1 = __builtin_amdgcn_mfma_f32_32x32x16_bf16(qf_c, kf1, fzero16(), 0, 0, 0);

        // ---- m-half 0: exp + pack + partner exchange -> bf00 (k 0-15), bf01 (k 16-31)
        unsigned g0 = packbf(__expf(s0[0]),  __expf(s0[1]));
        unsigned g1 = packbf(__expf(s0[2]),  __expf(s0[3]));
        unsigned g2 = packbf(__expf(s0[4]),  __expf(s0[5]));
        unsigned g3 = packbf(__expf(s0[6]),  __expf(s0[7]));
        unsigned g4 = packbf(__expf(s0[8]),  __expf(s0[9]));
        unsigned g5 = packbf(__expf(s0[10]), __expf(s0[11]));
        unsigned g6 = packbf(__expf(s0[12]), __expf(s0[13]));
        unsigned g7 = packbf(__expf(s0[14]), __expf(s0[15]));
        unsigned gr0 = (unsigned)__shfl_xor((int)(hi ? g0 : g2), 32);
        unsigned gr1 = (unsigned)__shfl_xor((int)(hi ? g1 : g3), 32);
        unsigned gr2 = (unsigned)__shfl_xor((int)(hi ? g4 : g6), 32);
        unsigned gr3 = (unsigned)__shfl_xor((int)(hi ? g5 : g7), 32);
        u32x4 b0u, b1u;
        b0u[0] = hi ? gr0 : g0;  b0u[1] = hi ? gr1 : g1;
        b0u[2] = hi ? g2 : gr0;  b0u[3] = hi ? g3 : gr1;
        b1u[0] = hi ? gr2 : g4;  b1u[1] = hi ? gr3 : g5;
        b1u[2] = hi ? g6 : gr2;  b1u[3] = hi ? g7 : gr3;
        bf16x8 bf00 = __builtin_bit_cast(bf16x8, b0u);
        bf16x8 bf01 = __builtin_bit_cast(bf16x8, b1u);

        // ---- m-half 1
        unsigned h0 = packbf(__expf(s1[0]),  __expf(s1[1]));
        unsigned h1 = packbf(__expf(s1[2]),  __expf(s1[3]));
        unsigned h2 = packbf(__expf(s1[4]),  __expf(s1[5]));
        unsigned h3 = packbf(__expf(s1[6]),  __expf(s1[7]));
        unsigned h4 = packbf(__expf(s1[8]),  __expf(s1[9]));
        unsigned h5 = packbf(__expf(s1[10]), __expf(s1[11]));
        unsigned h6 = packbf(__expf(s1[12]), __expf(s1[13]));
        unsigned h7 = packbf(__expf(s1[14]), __expf(s1[15]));
        unsigned hr0 = (unsigned)__shfl_xor((int)(hi ? h0 : h2), 32);
        unsigned hr1 = (unsigned)__shfl_xor((int)(hi ? h1 : h3), 32);
        unsigned hr2 = (unsigned)__shfl_xor((int)(hi ? h4 : h6), 32);
        unsigned hr3 = (unsigned)__shfl_xor((int)(hi ? h5 : h7), 32);
        u32x4 b2u, b3u;
        b2u[0] = hi ? hr0 : h0;  b2u[1] = hi ? hr1 : h1;
        b2u[2] = hi ? h2 : hr0;  b2u[3] = hi ? h3 : hr1;
        b3u[0] = hi ? hr2 : h4;  b3u[1] = hi ? hr3 : h5;
        b3u[2] = hi ? h6 : hr2;  b3u[3] = hi ? h7 : hr3;
        bf16x8 bf10 = __builtin_bit_cast(bf16x8, b2u);
        bf16x8 bf11 = __builtin_bit_cast(bf16x8, b3u);

        accA = __builtin_amdgcn_mfma_f32_32x32x16_bf16(a00_c, bf00, accA, 0, 0, 0);
        accA = __builtin_amdgcn_mfma_f32_32x32x16_bf16(a01_c, bf01, accA, 0, 0, 0);
        accC = __builtin_amdgcn_mfma_f32_32x32x16_bf16(a10_c, bf00, accC, 0, 0, 0);
        accC = __builtin_amdgcn_mfma_f32_32x32x16_bf16(a11_c, bf01, accC, 0, 0, 0);
        accB = __builtin_amdgcn_mfma_f32_32x32x16_bf16(a00_c, bf10, accB, 0, 0, 0);
        accB = __builtin_amdgcn_mfma_f32_32x32x16_bf16(a01_c, bf11, accB, 0, 0, 0);
        accD = __builtin_amdgcn_mfma_f32_32x32x16_bf16(a10_c, bf10, accD, 0, 0, 0);
        accD = __builtin_amdgcn_mfma_f32_32x32x16_bf16(a11_c, bf11, accD, 0, 0, 0);

        qf_c = qf_n;
        a00_c = a00_n; a01_c = a01_n; a10_c = a10_n; a11_c = a11_n;
    }

    // two-stage reduce: waves 4-7 dump, waves 0-3 merge, then final sum
    int q4 = w & 3;
    if (w >= 4) {
#pragma unroll
        for (int r = 0; r < 16; ++r) {
            int rowr = (r & 3) + 8 * (r >> 2) + 4 * hi;
            red[q4][rowr][ml]           = accA[r];
            red[q4][rowr][32 + ml]      = accB[r];
            red[q4][rowr + 32][ml]      = accC[r];
            red[q4][rowr + 32][32 + ml] = accD[r];
        }
    }
    __syncthreads();
    if (w < 4) {
#pragma unroll
        for (int r = 0; r < 16; ++r) {
            int rowr = (r & 3) + 8 * (r >> 2) + 4 * hi;
            red[q4][rowr][ml]           += accA[r];
            red[q4][rowr][32 + ml]      += accB[r];
            red[q4][rowr + 32][ml]      += accC[r];
            red[q4][rowr + 32][32 + ml] += accD[r];
        }
    }
    __syncthreads();

    int c = t >> 3;
    int m0 = (t & 7) << 3;
    float4 s0 = *(float4*)&red[0][c][m0];
    float4 s1 = *(float4*)&red[0][c][m0 + 4];
#pragma unroll
    for (int q = 1; q < 4; ++q) {
        float4 a = *(float4*)&red[q][c][m0];
        float4 b4 = *(float4*)&red[q][c][m0 + 4];
        s0.x += a.x; s0.y += a.y; s0.z += a.z; s0.w += a.w;
        s1.x += b4.x; s1.y += b4.y; s1.z += b4.z; s1.w += b4.w;
    }
    size_t idx = ((size_t)(b * CC + c)) * NN + mbase + m0;
    float4 xa = *(const float4*)(x + idx);
    float4 xb = *(const float4*)(x + idx + 4);
    s0.x += xa.x; s0.y += xa.y; s0.z += xa.z; s0.w += xa.w;
    s1.x += xb.x; s1.y += xb.y; s1.z += xb.z; s1.w += xb.w;
    *(float4*)(out + idx) = s0;
    *(float4*)(out + idx + 4) = s1;
}

// ---------------------------------------------------------------------------
extern "C" void kernel_launch(void* const* d_in, const int* in_sizes, int n_in,
                              void* d_out, int out_size, void* d_ws, size_t ws_size,
                              hipStream_t stream) {
    const float* x  = (const float*)d_in[0];
    const float* wq = (const float*)d_in[1];
    const float* bq = (const float*)d_in[2];
    const float* wk = (const float*)d_in[3];
    const float* bk = (const float*)d_in[4];
    const float* wv = (const float*)d_in[5];
    const float* bv = (const float*)d_in[6];
    float* out = (float*)d_out;

    char* ws = (char*)d_ws;
    short* qb   = (short*)(ws);                              // 256 KB
    short* kb   = (short*)(ws + (256u << 10));               // 256 KB
    float* vT   = (float*)(ws + (512u << 10));               // 4 MB
    short* vsT  = (short*)(ws + (512u << 10) + (4u << 20));  // 2 MB
    float* rinv = (float*)(ws + (512u << 10) + (6u << 20));  // 64 KB

    proj_all  <<<384, 256, 0, stream>>>(x, wq, bq, wk, bk, wv, bv, qb, kb, vT);
    stats_mfma<<<512, 512, 0, stream>>>(qb, kb, rinv);
    v_scale   <<<512, 256, 0, stream>>>(vT, rinv, vsT);
    attn_pv   <<<256, 512, 0, stream>>>(qb, kb, vsT, x, out);
}

// Round 13
// 48.178 us; speedup vs baseline: 1.0368x; 1.0065x over previous
//
#include <hip/hip_runtime.h>
#include <hip/hip_bf16.h>
#include <math.h>

#define NN 4096
#define CC 64

typedef float  f32x16 __attribute__((ext_vector_type(16)));
typedef short  bf16x8 __attribute__((ext_vector_type(8)));
typedef short  s16x4  __attribute__((ext_vector_type(4)));
typedef unsigned int u32x4 __attribute__((ext_vector_type(4)));

static __device__ __forceinline__ unsigned short f2bfu(float f) {
    __hip_bfloat16 h = __float2bfloat16(f);
    unsigned short s;
    __builtin_memcpy(&s, &h, 2);
    return s;
}
static __device__ __forceinline__ unsigned packbf(float lo, float hi) {
    return (unsigned)f2bfu(lo) | ((unsigned)f2bfu(hi) << 16);
}
static __device__ __forceinline__ f32x16 fzero16() {
    f32x16 z;
#pragma unroll
    for (int i = 0; i < 16; ++i) z[i] = 0.f;
    return z;
}
static __device__ __forceinline__ bf16x8 bzero8() {
    bf16x8 z;
#pragma unroll
    for (int i = 0; i < 8; ++i) z[i] = 0;
    return z;
}

// P-half processing: __expf -> bf16 pack -> lane^32 partner exchange -> 4 PV
// MFMAs (2 per c-half accumulator).  Bit-identical machinery to R7/R12.
static __device__ __forceinline__ void process_phalf(
        const f32x16& s, int hi,
        bf16x8 a0, bf16x8 a1, bf16x8 a2, bf16x8 a3,
        f32x16& accX, f32x16& accY) {
    unsigned g0 = packbf(__expf(s[0]),  __expf(s[1]));
    unsigned g1 = packbf(__expf(s[2]),  __expf(s[3]));
    unsigned g2 = packbf(__expf(s[4]),  __expf(s[5]));
    unsigned g3 = packbf(__expf(s[6]),  __expf(s[7]));
    unsigned g4 = packbf(__expf(s[8]),  __expf(s[9]));
    unsigned g5 = packbf(__expf(s[10]), __expf(s[11]));
    unsigned g6 = packbf(__expf(s[12]), __expf(s[13]));
    unsigned g7 = packbf(__expf(s[14]), __expf(s[15]));
    unsigned r0 = (unsigned)__shfl_xor((int)(hi ? g0 : g2), 32);
    unsigned r1 = (unsigned)__shfl_xor((int)(hi ? g1 : g3), 32);
    unsigned r2 = (unsigned)__shfl_xor((int)(hi ? g4 : g6), 32);
    unsigned r3 = (unsigned)__shfl_xor((int)(hi ? g5 : g7), 32);
    u32x4 b0u, b1u;
    b0u[0] = hi ? r0 : g0;  b0u[1] = hi ? r1 : g1;
    b0u[2] = hi ? g2 : r0;  b0u[3] = hi ? g3 : r1;
    b1u[0] = hi ? r2 : g4;  b1u[1] = hi ? r3 : g5;
    b1u[2] = hi ? g6 : r2;  b1u[3] = hi ? g7 : r3;
    bf16x8 bf0 = __builtin_bit_cast(bf16x8, b0u);
    bf16x8 bf1 = __builtin_bit_cast(bf16x8, b1u);
    accX = __builtin_amdgcn_mfma_f32_32x32x16_bf16(a0, bf0, accX, 0, 0, 0);
    accX = __builtin_amdgcn_mfma_f32_32x32x16_bf16(a1, bf1, accX, 0, 0, 0);
    accY = __builtin_amdgcn_mfma_f32_32x32x16_bf16(a2, bf0, accY, 0, 0, 0);
    accY = __builtin_amdgcn_mfma_f32_32x32x16_bf16(a3, bf1, accY, 0, 0, 0);
}

// ---------------------------------------------------------------------------
// K1: fused projection (q,k,v) via MFMA.  (R12 verbatim)
// ---------------------------------------------------------------------------
__global__ __launch_bounds__(256) void proj_all(
        const float* __restrict__ x,
        const float* __restrict__ wq, const float* __restrict__ bq,
        const float* __restrict__ wk, const float* __restrict__ bk,
        const float* __restrict__ wv, const float* __restrict__ bv,
        short* __restrict__ qb, short* __restrict__ kb, float* __restrict__ vT) {
    int t = threadIdx.x;
    int w = t >> 6, ml = t & 31, hi = (t >> 5) & 1;
    int rt = blockIdx.x >> 7;
    int nt = (blockIdx.x & 127) * 4 + w;
    int ng = nt * 32 + ml;            // b*4096+n
    int b = ng >> 12, nb_ = ng & 4095;
    const float* xc = x + ((size_t)b * CC) * NN + nb_;

    int rg = 32 * rt + ml;            // my A-row (W row)
    const float* wrow =
        rg < 8  ? wq + (size_t)rg * 64 :
        rg < 16 ? wk + (size_t)(rg - 8) * 64 :
        rg < 80 ? wv + (size_t)(rg - 16) * 64 : wq;
    bool wvalid = (rg < 80);

    f32x16 acc = fzero16();
#pragma unroll
    for (int s = 0; s < 4; ++s) {
        int c0 = 16 * s + 8 * hi;
        float xv[8];
#pragma unroll
        for (int j = 0; j < 8; ++j) xv[j] = xc[(size_t)(c0 + j) * NN];
        u32x4 xg;
#pragma unroll
        for (int j = 0; j < 4; ++j) xg[j] = packbf(xv[2 * j], xv[2 * j + 1]);
        bf16x8 xf = __builtin_bit_cast(bf16x8, xg);

        bf16x8 af;
        if (wvalid) {
            float4 f0 = *(const float4*)(wrow + c0);
            float4 f1 = *(const float4*)(wrow + c0 + 4);
            u32x4 ag;
            ag[0] = packbf(f0.x, f0.y); ag[1] = packbf(f0.z, f0.w);
            ag[2] = packbf(f1.x, f1.y); ag[3] = packbf(f1.z, f1.w);
            af = __builtin_bit_cast(bf16x8, ag);
        } else {
            af = bzero8();
        }
        acc = __builtin_amdgcn_mfma_f32_32x32x16_bf16(af, xf, acc, 0, 0, 0);
    }

    if (rt == 0) {
        s16x4 qv, kv;
#pragma unroll
        for (int j = 0; j < 4; ++j) {
            qv[j] = (short)f2bfu(acc[j] + bq[j + 4 * hi]);
            kv[j] = (short)f2bfu(acc[j + 4] + bk[j + 4 * hi]);
        }
        *(s16x4*)(qb + (size_t)ng * 8 + 4 * hi) = qv;
        *(s16x4*)(kb + (size_t)ng * 8 + 4 * hi) = kv;
#pragma unroll
        for (int r = 8; r < 16; ++r) {            // rows 16-31 -> v c 0-15
            int rowr = (r & 3) + 8 * (r >> 2) + 4 * hi;
            int c = rowr - 16;
            vT[((size_t)(b * CC + c)) * NN + nb_] = acc[r] + bv[c];
        }
    } else if (rt == 1) {
#pragma unroll
        for (int r = 0; r < 16; ++r) {            // rows 32-63 -> v c 16-47
            int rowr = (r & 3) + 8 * (r >> 2) + 4 * hi;
            int c = rowr + 16;
            vT[((size_t)(b * CC + c)) * NN + nb_] = acc[r] + bv[c];
        }
    } else {
#pragma unroll
        for (int r = 0; r < 8; ++r) {             // rows 64-79 -> v c 48-63
            int rowr = (r & 3) + 8 * (r >> 2) + 4 * hi;
            int c = rowr + 48;
            vT[((size_t)(b * CC + c)) * NN + nb_] = acc[r] + bv[c];
        }
    }
}

// ---------------------------------------------------------------------------
// K2: rinv[b][n] = 1/sum_m exp(s[n][m]).  (R12 verbatim)
// ---------------------------------------------------------------------------
__global__ __launch_bounds__(512) void stats_mfma(
        const short* __restrict__ qb, const short* __restrict__ kb,
        float* __restrict__ rinv) {
    int b = blockIdx.x >> 7;
    int nbase = (blockIdx.x & 127) * 32;
    int t = threadIdx.x;
    int w = __builtin_amdgcn_readfirstlane(t >> 6);
    int ml = t & 31, hi = (t >> 5) & 1;

    bf16x8 qf = bzero8();
    if (!hi) qf = *(const bf16x8*)(qb + ((size_t)(b * NN + nbase + ml)) * 8);
    const short* kbb = kb + ((size_t)b * NN) * 8;

    float accl[16];
#pragma unroll
    for (int r = 0; r < 16; ++r) accl[r] = 0.f;

    bf16x8 kf0 = bzero8();
    if (!hi) kf0 = *(const bf16x8*)(kbb + (size_t)(w * 32 + ml) * 8);

    for (int i = 0; i < 16; ++i) {
        int mchn = (i < 15) ? (w + 8 * (i + 1)) : w;
        bf16x8 kf1 = bzero8();
        if (!hi) kf1 = *(const bf16x8*)(kbb + (size_t)(mchn * 32 + ml) * 8);
        f32x16 s = __builtin_amdgcn_mfma_f32_32x32x16_bf16(qf, kf0, fzero16(), 0, 0, 0);
#pragma unroll
        for (int r = 0; r < 16; ++r) accl[r] += __expf(s[r]);
        kf0 = kf1;
    }

#pragma unroll
    for (int r = 0; r < 16; ++r) {
#pragma unroll
        for (int mask = 1; mask <= 16; mask <<= 1)
            accl[r] += __shfl_xor(accl[r], mask);
    }

    __shared__ float rs[32];
    if (t < 32) rs[t] = 0.f;
    __syncthreads();
    if (ml == 0) {
#pragma unroll
        for (int r = 0; r < 16; ++r) {
            int rowr = (r & 3) + 8 * (r >> 2) + 4 * hi;
            atomicAdd(&rs[rowr], accl[r]);
        }
    }
    __syncthreads();
    if (t < 32) rinv[(size_t)b * NN + nbase + t] = 1.0f / rs[t];
}

// ---------------------------------------------------------------------------
// K3: vsT[c][n] = bf16(vT[c][n] * rinv[n])   (R12 verbatim)
// ---------------------------------------------------------------------------
__global__ __launch_bounds__(256) void v_scale(
        const float* __restrict__ vT, const float* __restrict__ rinv,
        short* __restrict__ vsT) {
    int gid = blockIdx.x * 256 + threadIdx.x;   // 131072 threads
    int row = gid >> 9;                         // b*64+c
    int noff = (gid & 511) << 3;
    int b = row >> 6;
    const float* vp = vT + (size_t)row * NN + noff;
    const float* rp = rinv + (size_t)b * NN + noff;
    float4 v0 = *(const float4*)vp, v1 = *(const float4*)(vp + 4);
    float4 r0 = *(const float4*)rp, r1 = *(const float4*)(rp + 4);
    u32x4 o;
    o[0] = packbf(v0.x * r0.x, v0.y * r0.y);
    o[1] = packbf(v0.z * r0.z, v0.w * r0.w);
    o[2] = packbf(v1.x * r1.x, v1.y * r1.y);
    o[3] = packbf(v1.z * r1.z, v1.w * r1.w);
    *(u32x4*)(vsT + (size_t)row * NN + noff) = o;
}

// ---------------------------------------------------------------------------
// K4: out[b][c][m] = x + sum_n Vs[c][n] * exp(s[n][m]).
// SINGLE VARIABLE vs R12: 1-chunk software pipeline (issue loads j+1 |
// process chunk j-1 | issue S-MFMAs chunk j), all-__expf numerics.
// Grid 256 = b x 64 m-tiles(64); 8-wave n-split, 16 chunks; no loop barriers.
// ---------------------------------------------------------------------------
__global__ __launch_bounds__(512, 2) void attn_pv(
        const short* __restrict__ qb, const short* __restrict__ kb,
        const short* __restrict__ vsT,
        const float* __restrict__ x, float* __restrict__ out) {
    __shared__ float red[4][64][68];

    int b = blockIdx.x >> 6;
    int mbase = (blockIdx.x & 63) << 6;
    int t = threadIdx.x;
    int w = __builtin_amdgcn_readfirstlane(t >> 6);   // 0..7 n-split
    int ml = t & 31, hi = (t >> 5) & 1;

    bf16x8 kf0 = bzero8(), kf1 = bzero8();
    if (!hi) {
        kf0 = *(const bf16x8*)(kb + ((size_t)(b * NN + mbase + ml)) * 8);
        kf1 = *(const bf16x8*)(kb + ((size_t)(b * NN + mbase + 32 + ml)) * 8);
    }

    f32x16 accA = fzero16(), accB = fzero16();   // (c0,m0) (c0,m1)
    f32x16 accC = fzero16(), accD = fzero16();   // (c1,m0) (c1,m1)

    const short* qbb = qb + ((size_t)b * NN) * 8;
    const short* v0p = vsT + ((size_t)(b * CC) + ml) * NN;
    const short* v1p = v0p + (size_t)32 * NN;

    // ---- prologue: chunk 0 frags + its S; chunk 1 frags into _c
    int n0 = w * 32;
    bf16x8 qf_c = bzero8();
    if (!hi) qf_c = *(const bf16x8*)(qbb + (size_t)(n0 + ml) * 8);
    bf16x8 a00_p = *(const bf16x8*)(v0p + n0 + 8 * hi);
    bf16x8 a01_p = *(const bf16x8*)(v0p + n0 + 16 + 8 * hi);
    bf16x8 a10_p = *(const bf16x8*)(v1p + n0 + 8 * hi);
    bf16x8 a11_p = *(const bf16x8*)(v1p + n0 + 16 + 8 * hi);

    f32x16 s0p = __builtin_amdgcn_mfma_f32_32x32x16_bf16(qf_c, kf0, fzero16(), 0, 0, 0);
    f32x16 s1p = __builtin_amdgcn_mfma_f32_32x32x16_bf16(qf_c, kf1, fzero16(), 0, 0, 0);

    int n1 = (w + 8) * 32;
    if (!hi) qf_c = *(const bf16x8*)(qbb + (size_t)(n1 + ml) * 8);
    else     qf_c = bzero8();
    bf16x8 a00_c = *(const bf16x8*)(v0p + n1 + 8 * hi);
    bf16x8 a01_c = *(const bf16x8*)(v0p + n1 + 16 + 8 * hi);
    bf16x8 a10_c = *(const bf16x8*)(v1p + n1 + 8 * hi);
    bf16x8 a11_c = *(const bf16x8*)(v1p + n1 + 16 + 8 * hi);

    for (int j = 1; j < 16; ++j) {
        // issue loads for chunk j+1 (wrap-reload chunk 0 on last iter, unused)
        int nn = (j < 15) ? (w + 8 * (j + 1)) * 32 : w * 32;
        bf16x8 qf_n = bzero8();
        if (!hi) qf_n = *(const bf16x8*)(qbb + (size_t)(nn + ml) * 8);
        bf16x8 a00_n = *(const bf16x8*)(v0p + nn + 8 * hi);
        bf16x8 a01_n = *(const bf16x8*)(v0p + nn + 16 + 8 * hi);
        bf16x8 a10_n = *(const bf16x8*)(v1p + nn + 8 * hi);
        bf16x8 a11_n = *(const bf16x8*)(v1p + nn + 16 + 8 * hi);

        // process chunk j-1 (saved S + its V-frags)
        process_phalf(s0p, hi, a00_p, a01_p, a10_p, a11_p, accA, accC);
        process_phalf(s1p, hi, a00_p, a01_p, a10_p, a11_p, accB, accD);

        // issue chunk j's S-MFMAs (consumed next iter)
        s0p = __builtin_amdgcn_mfma_f32_32x32x16_bf16(qf_c, kf0, fzero16(), 0, 0, 0);
        s1p = __builtin_amdgcn_mfma_f32_32x32x16_bf16(qf_c, kf1, fzero16(), 0, 0, 0);

        a00_p = a00_c; a01_p = a01_c; a10_p = a10_c; a11_p = a11_c;
        a00_c = a00_n; a01_c = a01_n; a10_c = a10_n; a11_c = a11_n;
        qf_c = qf_n;
    }
    // epilogue: chunk 15
    process_phalf(s0p, hi, a00_p, a01_p, a10_p, a11_p, accA, accC);
    process_phalf(s1p, hi, a00_p, a01_p, a10_p, a11_p, accB, accD);

    // two-stage reduce: waves 4-7 dump, waves 0-3 merge, then final sum
    int q4 = w & 3;
    if (w >= 4) {
#pragma unroll
        for (int r = 0; r < 16; ++r) {
            int rowr = (r & 3) + 8 * (r >> 2) + 4 * hi;
            red[q4][rowr][ml]           = accA[r];
            red[q4][rowr][32 + ml]      = accB[r];
            red[q4][rowr + 32][ml]      = accC[r];
            red[q4][rowr + 32][32 + ml] = accD[r];
        }
    }
    __syncthreads();
    if (w < 4) {
#pragma unroll
        for (int r = 0; r < 16; ++r) {
            int rowr = (r & 3) + 8 * (r >> 2) + 4 * hi;
            red[q4][rowr][ml]           += accA[r];
            red[q4][rowr][32 + ml]      += accB[r];
            red[q4][rowr + 32][ml]      += accC[r];
            red[q4][rowr + 32][32 + ml] += accD[r];
        }
    }
    __syncthreads();

    int c = t >> 3;
    int m0 = (t & 7) << 3;
    float4 s0 = *(float4*)&red[0][c][m0];
    float4 s1 = *(float4*)&red[0][c][m0 + 4];
#pragma unroll
    for (int q = 1; q < 4; ++q) {
        float4 a = *(float4*)&red[q][c][m0];
        float4 b4 = *(float4*)&red[q][c][m0 + 4];
        s0.x += a.x; s0.y += a.y; s0.z += a.z; s0.w += a.w;
        s1.x += b4.x; s1.y += b4.y; s1.z += b4.z; s1.w += b4.w;
    }
    size_t idx = ((size_t)(b * CC + c)) * NN + mbase + m0;
    float4 xa = *(const float4*)(x + idx);
    float4 xb = *(const float4*)(x + idx + 4);
    s0.x += xa.x; s0.y += xa.y; s0.z += xa.z; s0.w += xa.w;
    s1.x += xb.x; s1.y += xb.y; s1.z += xb.z; s1.w += xb.w;
    *(float4*)(out + idx) = s0;
    *(float4*)(out + idx + 4) = s1;
}

// ---------------------------------------------------------------------------
extern "C" void kernel_launch(void* const* d_in, const int* in_sizes, int n_in,
                              void* d_out, int out_size, void* d_ws, size_t ws_size,
                              hipStream_t stream) {
    const float* x  = (const float*)d_in[0];
    const float* wq = (const float*)d_in[1];
    const float* bq = (const float*)d_in[2];
    const float* wk = (const float*)d_in[3];
    const float* bk = (const float*)d_in[4];
    const float* wv = (const float*)d_in[5];
    const float* bv = (const float*)d_in[6];
    float* out = (float*)d_out;

    char* ws = (char*)d_ws;
    short* qb   = (short*)(ws);                              // 256 KB
    short* kb   = (short*)(ws + (256u << 10));               // 256 KB
    float* vT   = (float*)(ws + (512u << 10));               // 4 MB
    short* vsT  = (short*)(ws + (512u << 10) + (4u << 20));  // 2 MB
    float* rinv = (float*)(ws + (512u << 10) + (6u << 20));  // 64 KB

    proj_all  <<<384, 256, 0, stream>>>(x, wq, bq, wk, bk, wv, bv, qb, kb, vT);
    stats_mfma<<<512, 512, 0, stream>>>(qb, kb, rinv);
    v_scale   <<<512, 256, 0, stream>>>(vT, rinv, vsT);
    attn_pv   <<<256, 512, 0, stream>>>(qb, kb, vsT, x, out);
}

// Round 14
// 46.173 us; speedup vs baseline: 1.0818x; 1.0434x over previous
//
#include <hip/hip_runtime.h>
#include <hip/hip_bf16.h>
#include <math.h>

#define NN 4096
#define CC 64

typedef float  f32x16 __attribute__((ext_vector_type(16)));
typedef short  bf16x8 __attribute__((ext_vector_type(8)));
typedef short  s16x4  __attribute__((ext_vector_type(4)));
typedef unsigned int u32x4 __attribute__((ext_vector_type(4)));

static __device__ __forceinline__ unsigned short f2bfu(float f) {
    __hip_bfloat16 h = __float2bfloat16(f);
    unsigned short s;
    __builtin_memcpy(&s, &h, 2);
    return s;
}
static __device__ __forceinline__ unsigned packbf(float lo, float hi) {
    return (unsigned)f2bfu(lo) | ((unsigned)f2bfu(hi) << 16);
}
static __device__ __forceinline__ f32x16 fzero16() {
    f32x16 z;
#pragma unroll
    for (int i = 0; i < 16; ++i) z[i] = 0.f;
    return z;
}
static __device__ __forceinline__ bf16x8 bzero8() {
    bf16x8 z;
#pragma unroll
    for (int i = 0; i < 8; ++i) z[i] = 0;
    return z;
}

// P-half processing: __expf -> bf16 pack -> lane^32 partner exchange -> 4 PV
// MFMAs (2 per c-half accumulator).
static __device__ __forceinline__ void process_phalf(
        const f32x16& s, int hi,
        bf16x8 a0, bf16x8 a1, bf16x8 a2, bf16x8 a3,
        f32x16& accX, f32x16& accY) {
    unsigned g0 = packbf(__expf(s[0]),  __expf(s[1]));
    unsigned g1 = packbf(__expf(s[2]),  __expf(s[3]));
    unsigned g2 = packbf(__expf(s[4]),  __expf(s[5]));
    unsigned g3 = packbf(__expf(s[6]),  __expf(s[7]));
    unsigned g4 = packbf(__expf(s[8]),  __expf(s[9]));
    unsigned g5 = packbf(__expf(s[10]), __expf(s[11]));
    unsigned g6 = packbf(__expf(s[12]), __expf(s[13]));
    unsigned g7 = packbf(__expf(s[14]), __expf(s[15]));
    unsigned r0 = (unsigned)__shfl_xor((int)(hi ? g0 : g2), 32);
    unsigned r1 = (unsigned)__shfl_xor((int)(hi ? g1 : g3), 32);
    unsigned r2 = (unsigned)__shfl_xor((int)(hi ? g4 : g6), 32);
    unsigned r3 = (unsigned)__shfl_xor((int)(hi ? g5 : g7), 32);
    u32x4 b0u, b1u;
    b0u[0] = hi ? r0 : g0;  b0u[1] = hi ? r1 : g1;
    b0u[2] = hi ? g2 : r0;  b0u[3] = hi ? g3 : r1;
    b1u[0] = hi ? r2 : g4;  b1u[1] = hi ? r3 : g5;
    b1u[2] = hi ? g6 : r2;  b1u[3] = hi ? g7 : r3;
    bf16x8 bf0 = __builtin_bit_cast(bf16x8, b0u);
    bf16x8 bf1 = __builtin_bit_cast(bf16x8, b1u);
    accX = __builtin_amdgcn_mfma_f32_32x32x16_bf16(a0, bf0, accX, 0, 0, 0);
    accX = __builtin_amdgcn_mfma_f32_32x32x16_bf16(a1, bf1, accX, 0, 0, 0);
    accY = __builtin_amdgcn_mfma_f32_32x32x16_bf16(a2, bf0, accY, 0, 0, 0);
    accY = __builtin_amdgcn_mfma_f32_32x32x16_bf16(a3, bf1, accY, 0, 0, 0);
}

// ---------------------------------------------------------------------------
// K1: fused projection (q,k,v) via MFMA.  (R13 verbatim)
// ---------------------------------------------------------------------------
__global__ __launch_bounds__(256) void proj_all(
        const float* __restrict__ x,
        const float* __restrict__ wq, const float* __restrict__ bq,
        const float* __restrict__ wk, const float* __restrict__ bk,
        const float* __restrict__ wv, const float* __restrict__ bv,
        short* __restrict__ qb, short* __restrict__ kb, float* __restrict__ vT) {
    int t = threadIdx.x;
    int w = t >> 6, ml = t & 31, hi = (t >> 5) & 1;
    int rt = blockIdx.x >> 7;
    int nt = (blockIdx.x & 127) * 4 + w;
    int ng = nt * 32 + ml;            // b*4096+n
    int b = ng >> 12, nb_ = ng & 4095;
    const float* xc = x + ((size_t)b * CC) * NN + nb_;

    int rg = 32 * rt + ml;            // my A-row (W row)
    const float* wrow =
        rg < 8  ? wq + (size_t)rg * 64 :
        rg < 16 ? wk + (size_t)(rg - 8) * 64 :
        rg < 80 ? wv + (size_t)(rg - 16) * 64 : wq;
    bool wvalid = (rg < 80);

    f32x16 acc = fzero16();
#pragma unroll
    for (int s = 0; s < 4; ++s) {
        int c0 = 16 * s + 8 * hi;
        float xv[8];
#pragma unroll
        for (int j = 0; j < 8; ++j) xv[j] = xc[(size_t)(c0 + j) * NN];
        u32x4 xg;
#pragma unroll
        for (int j = 0; j < 4; ++j) xg[j] = packbf(xv[2 * j], xv[2 * j + 1]);
        bf16x8 xf = __builtin_bit_cast(bf16x8, xg);

        bf16x8 af;
        if (wvalid) {
            float4 f0 = *(const float4*)(wrow + c0);
            float4 f1 = *(const float4*)(wrow + c0 + 4);
            u32x4 ag;
            ag[0] = packbf(f0.x, f0.y); ag[1] = packbf(f0.z, f0.w);
            ag[2] = packbf(f1.x, f1.y); ag[3] = packbf(f1.z, f1.w);
            af = __builtin_bit_cast(bf16x8, ag);
        } else {
            af = bzero8();
        }
        acc = __builtin_amdgcn_mfma_f32_32x32x16_bf16(af, xf, acc, 0, 0, 0);
    }

    if (rt == 0) {
        s16x4 qv, kv;
#pragma unroll
        for (int j = 0; j < 4; ++j) {
            qv[j] = (short)f2bfu(acc[j] + bq[j + 4 * hi]);
            kv[j] = (short)f2bfu(acc[j + 4] + bk[j + 4 * hi]);
        }
        *(s16x4*)(qb + (size_t)ng * 8 + 4 * hi) = qv;
        *(s16x4*)(kb + (size_t)ng * 8 + 4 * hi) = kv;
#pragma unroll
        for (int r = 8; r < 16; ++r) {            // rows 16-31 -> v c 0-15
            int rowr = (r & 3) + 8 * (r >> 2) + 4 * hi;
            int c = rowr - 16;
            vT[((size_t)(b * CC + c)) * NN + nb_] = acc[r] + bv[c];
        }
    } else if (rt == 1) {
#pragma unroll
        for (int r = 0; r < 16; ++r) {            // rows 32-63 -> v c 16-47
            int rowr = (r & 3) + 8 * (r >> 2) + 4 * hi;
            int c = rowr + 16;
            vT[((size_t)(b * CC + c)) * NN + nb_] = acc[r] + bv[c];
        }
    } else {
#pragma unroll
        for (int r = 0; r < 8; ++r) {             // rows 64-79 -> v c 48-63
            int rowr = (r & 3) + 8 * (r >> 2) + 4 * hi;
            int c = rowr + 48;
            vT[((size_t)(b * CC + c)) * NN + nb_] = acc[r] + bv[c];
        }
    }
}

// ---------------------------------------------------------------------------
// K2: rowsum via MFMA (R13 main loop verbatim), then FUSED epilogue scales
// this block's 32-n window of V: vsT[c][n] = bf16(vT[c][n] / rowsum[n]).
// Single variable vs R13: replaces the separate v_scale kernel.
// Grid 512 = b x 128 n-tiles(32); 8 waves m-split, 16 iters.
// ---------------------------------------------------------------------------
__global__ __launch_bounds__(512) void stats_mfma(
        const short* __restrict__ qb, const short* __restrict__ kb,
        const float* __restrict__ vT, short* __restrict__ vsT) {
    int b = blockIdx.x >> 7;
    int nbase = (blockIdx.x & 127) * 32;
    int t = threadIdx.x;
    int w = __builtin_amdgcn_readfirstlane(t >> 6);
    int ml = t & 31, hi = (t >> 5) & 1;

    bf16x8 qf = bzero8();
    if (!hi) qf = *(const bf16x8*)(qb + ((size_t)(b * NN + nbase + ml)) * 8);
    const short* kbb = kb + ((size_t)b * NN) * 8;

    float accl[16];
#pragma unroll
    for (int r = 0; r < 16; ++r) accl[r] = 0.f;

    bf16x8 kf0 = bzero8();
    if (!hi) kf0 = *(const bf16x8*)(kbb + (size_t)(w * 32 + ml) * 8);

    for (int i = 0; i < 16; ++i) {
        int mchn = (i < 15) ? (w + 8 * (i + 1)) : w;
        bf16x8 kf1 = bzero8();
        if (!hi) kf1 = *(const bf16x8*)(kbb + (size_t)(mchn * 32 + ml) * 8);
        f32x16 s = __builtin_amdgcn_mfma_f32_32x32x16_bf16(qf, kf0, fzero16(), 0, 0, 0);
#pragma unroll
        for (int r = 0; r < 16; ++r) accl[r] += __expf(s[r]);
        kf0 = kf1;
    }

#pragma unroll
    for (int r = 0; r < 16; ++r) {
#pragma unroll
        for (int mask = 1; mask <= 16; mask <<= 1)
            accl[r] += __shfl_xor(accl[r], mask);
    }

    __shared__ float rs[32];
    if (t < 32) rs[t] = 0.f;
    __syncthreads();
    if (ml == 0) {
#pragma unroll
        for (int r = 0; r < 16; ++r) {
            int rowr = (r & 3) + 8 * (r >> 2) + 4 * hi;
            atomicAdd(&rs[rowr], accl[r]);
        }
    }
    __syncthreads();

    // fused epilogue: scale V columns in this 32-n window (single bf16 round,
    // same value as the old v_scale kernel: inv = 1/rowsum)
    float inv = 1.0f / rs[t & 31];
    int nl = nbase + (t & 31);
#pragma unroll
    for (int cl = 0; cl < 4; ++cl) {
        int c = 16 * cl + (t >> 5);
        size_t idx = ((size_t)(b * CC + c)) * NN + nl;
        vsT[idx] = (short)f2bfu(vT[idx] * inv);
    }
}

// ---------------------------------------------------------------------------
// K3: out[b][c][m] = x + sum_n Vs[c][n] * exp(s[n][m]).  (R13 verbatim:
// 1-chunk software pipeline, all-__expf numerics.)
// Grid 256 = b x 64 m-tiles(64); 8-wave n-split, 16 chunks; no loop barriers.
// ---------------------------------------------------------------------------
__global__ __launch_bounds__(512, 2) void attn_pv(
        const short* __restrict__ qb, const short* __restrict__ kb,
        const short* __restrict__ vsT,
        const float* __restrict__ x, float* __restrict__ out) {
    __shared__ float red[4][64][68];

    int b = blockIdx.x >> 6;
    int mbase = (blockIdx.x & 63) << 6;
    int t = threadIdx.x;
    int w = __builtin_amdgcn_readfirstlane(t >> 6);   // 0..7 n-split
    int ml = t & 31, hi = (t >> 5) & 1;

    bf16x8 kf0 = bzero8(), kf1 = bzero8();
    if (!hi) {
        kf0 = *(const bf16x8*)(kb + ((size_t)(b * NN + mbase + ml)) * 8);
        kf1 = *(const bf16x8*)(kb + ((size_t)(b * NN + mbase + 32 + ml)) * 8);
    }

    f32x16 accA = fzero16(), accB = fzero16();   // (c0,m0) (c0,m1)
    f32x16 accC = fzero16(), accD = fzero16();   // (c1,m0) (c1,m1)

    const short* qbb = qb + ((size_t)b * NN) * 8;
    const short* v0p = vsT + ((size_t)(b * CC) + ml) * NN;
    const short* v1p = v0p + (size_t)32 * NN;

    // ---- prologue: chunk 0 frags + its S; chunk 1 frags into _c
    int n0 = w * 32;
    bf16x8 qf_c = bzero8();
    if (!hi) qf_c = *(const bf16x8*)(qbb + (size_t)(n0 + ml) * 8);
    bf16x8 a00_p = *(const bf16x8*)(v0p + n0 + 8 * hi);
    bf16x8 a01_p = *(const bf16x8*)(v0p + n0 + 16 + 8 * hi);
    bf16x8 a10_p = *(const bf16x8*)(v1p + n0 + 8 * hi);
    bf16x8 a11_p = *(const bf16x8*)(v1p + n0 + 16 + 8 * hi);

    f32x16 s0p = __builtin_amdgcn_mfma_f32_32x32x16_bf16(qf_c, kf0, fzero16(), 0, 0, 0);
    f32x16 s1p = __builtin_amdgcn_mfma_f32_32x32x16_bf16(qf_c, kf1, fzero16(), 0, 0, 0);

    int n1 = (w + 8) * 32;
    if (!hi) qf_c = *(const bf16x8*)(qbb + (size_t)(n1 + ml) * 8);
    else     qf_c = bzero8();
    bf16x8 a00_c = *(const bf16x8*)(v0p + n1 + 8 * hi);
    bf16x8 a01_c = *(const bf16x8*)(v0p + n1 + 16 + 8 * hi);
    bf16x8 a10_c = *(const bf16x8*)(v1p + n1 + 8 * hi);
    bf16x8 a11_c = *(const bf16x8*)(v1p + n1 + 16 + 8 * hi);

    for (int j = 1; j < 16; ++j) {
        // issue loads for chunk j+1 (wrap-reload chunk 0 on last iter, unused)
        int nn = (j < 15) ? (w + 8 * (j + 1)) * 32 : w * 32;
        bf16x8 qf_n = bzero8();
        if (!hi) qf_n = *(const bf16x8*)(qbb + (size_t)(nn + ml) * 8);
        bf16x8 a00_n = *(const bf16x8*)(v0p + nn + 8 * hi);
        bf16x8 a01_n = *(const bf16x8*)(v0p + nn + 16 + 8 * hi);
        bf16x8 a10_n = *(const bf16x8*)(v1p + nn + 8 * hi);
        bf16x8 a11_n = *(const bf16x8*)(v1p + nn + 16 + 8 * hi);

        // process chunk j-1 (saved S + its V-frags)
        process_phalf(s0p, hi, a00_p, a01_p, a10_p, a11_p, accA, accC);
        process_phalf(s1p, hi, a00_p, a01_p, a10_p, a11_p, accB, accD);

        // issue chunk j's S-MFMAs (consumed next iter)
        s0p = __builtin_amdgcn_mfma_f32_32x32x16_bf16(qf_c, kf0, fzero16(), 0, 0, 0);
        s1p = __builtin_amdgcn_mfma_f32_32x32x16_bf16(qf_c, kf1, fzero16(), 0, 0, 0);

        a00_p = a00_c; a01_p = a01_c; a10_p = a10_c; a11_p = a11_c;
        a00_c = a00_n; a01_c = a01_n; a10_c = a10_n; a11_c = a11_n;
        qf_c = qf_n;
    }
    // epilogue: chunk 15
    process_phalf(s0p, hi, a00_p, a01_p, a10_p, a11_p, accA, accC);
    process_phalf(s1p, hi, a00_p, a01_p, a10_p, a11_p, accB, accD);

    // two-stage reduce: waves 4-7 dump, waves 0-3 merge, then final sum
    int q4 = w & 3;
    if (w >= 4) {
#pragma unroll
        for (int r = 0; r < 16; ++r) {
            int rowr = (r & 3) + 8 * (r >> 2) + 4 * hi;
            red[q4][rowr][ml]           = accA[r];
            red[q4][rowr][32 + ml]      = accB[r];
            red[q4][rowr + 32][ml]      = accC[r];
            red[q4][rowr + 32][32 + ml] = accD[r];
        }
    }
    __syncthreads();
    if (w < 4) {
#pragma unroll
        for (int r = 0; r < 16; ++r) {
            int rowr = (r & 3) + 8 * (r >> 2) + 4 * hi;
            red[q4][rowr][ml]           += accA[r];
            red[q4][rowr][32 + ml]      += accB[r];
            red[q4][rowr + 32][ml]      += accC[r];
            red[q4][rowr + 32][32 + ml] += accD[r];
        }
    }
    __syncthreads();

    int c = t >> 3;
    int m0 = (t & 7) << 3;
    float4 s0 = *(float4*)&red[0][c][m0];
    float4 s1 = *(float4*)&red[0][c][m0 + 4];
#pragma unroll
    for (int q = 1; q < 4; ++q) {
        float4 a = *(float4*)&red[q][c][m0];
        float4 b4 = *(float4*)&red[q][c][m0 + 4];
        s0.x += a.x; s0.y += a.y; s0.z += a.z; s0.w += a.w;
        s1.x += b4.x; s1.y += b4.y; s1.z += b4.z; s1.w += b4.w;
    }
    size_t idx = ((size_t)(b * CC + c)) * NN + mbase + m0;
    float4 xa = *(const float4*)(x + idx);
    float4 xb = *(const float4*)(x + idx + 4);
    s0.x += xa.x; s0.y += xa.y; s0.z += xa.z; s0.w += xa.w;
    s1.x += xb.x; s1.y += xb.y; s1.z += xb.z; s1.w += xb.w;
    *(float4*)(out + idx) = s0;
    *(float4*)(out + idx + 4) = s1;
}

// ---------------------------------------------------------------------------
extern "C" void kernel_launch(void* const* d_in, const int* in_sizes, int n_in,
                              void* d_out, int out_size, void* d_ws, size_t ws_size,
                              hipStream_t stream) {
    const float* x  = (const float*)d_in[0];
    const float* wq = (const float*)d_in[1];
    const float* bq = (const float*)d_in[2];
    const float* wk = (const float*)d_in[3];
    const float* bk = (const float*)d_in[4];
    const float* wv = (const float*)d_in[5];
    const float* bv = (const float*)d_in[6];
    float* out = (float*)d_out;

    char* ws = (char*)d_ws;
    short* qb  = (short*)(ws);                              // 256 KB
    short* kb  = (short*)(ws + (256u << 10));               // 256 KB
    float* vT  = (float*)(ws + (512u << 10));               // 4 MB
    short* vsT = (short*)(ws + (512u << 10) + (4u << 20));  // 2 MB

    proj_all  <<<384, 256, 0, stream>>>(x, wq, bq, wk, bk, wv, bv, qb, kb, vT);
    stats_mfma<<<512, 512, 0, stream>>>(qb, kb, vT, vsT);
    attn_pv   <<<256, 512, 0, stream>>>(qb, kb, vsT, x, out);
}